// Round 8
// baseline (312.320 us; speedup 1.0000x reference)
//
#include <hip/hip_runtime.h>

// B=8, C=d=128, H=W=64, N=H*W=4096
#define NB 8
#define CD 128
#define NN 4096
#define KV 64                  // kv keys per tile
#define SCALE 0.08838834764831845f
#define L2E 1.44269504088896f
#define QSCALE (SCALE * L2E)   // fold softmax scale AND log2(e) into Q

typedef __bf16 bf16x8 __attribute__((ext_vector_type(8)));
typedef float f32x4 __attribute__((ext_vector_type(4)));

// XOR swizzles on 16B blocks within a row; involution -> same fn write & read.
__device__ __forceinline__ unsigned swz256(unsigned row, unsigned b) {
  unsigned s = b >> 4, o = b & 15u;
  unsigned sw = (s & 8u) | ((s & 7u) ^ (row & 7u));
  return row * 256u + sw * 16u + o;
}
__device__ __forceinline__ unsigned swz128(unsigned row, unsigned b) {
  unsigned s = b >> 4, o = b & 15u;
  unsigned sw = (s ^ row) & 7u;
  return row * 128u + sw * 16u + o;
}

// v_cvt_pk_bf16_f32: dst = {bf16(lo) in [15:0], bf16(hi) in [31:16]}
__device__ __forceinline__ int cvt_pk_bf16(float lo, float hi) {
  int w;
  asm("v_cvt_pk_bf16_f32 %0, %1, %2" : "=v"(w) : "v"(lo), "v"(hi));
  return w;
}

// ---------------------------------------------------------------------------
// Kernel 1: fused transpose + QKV projection (unchanged from v3).
// ---------------------------------------------------------------------------
__global__ __launch_bounds__(256, 2) void qkv_kernel(
    const float* __restrict__ x,
    const float* __restrict__ qw, const float* __restrict__ qb,
    const float* __restrict__ kw, const float* __restrict__ kb,
    const float* __restrict__ vw, const float* __restrict__ vb,
    __bf16* __restrict__ Qh, __bf16* __restrict__ Ql,
    __bf16* __restrict__ Kh, __bf16* __restrict__ Kl,
    __bf16* __restrict__ Vt)
{
  __shared__ __align__(16) unsigned char sm[49664];
  const int tid = threadIdx.x;
  const int lane = tid & 63, wv = tid >> 6;
  const int l15 = lane & 15, g = lane >> 4;
  const int b = blockIdx.x & 7;
  const int n0 = (blockIdx.x >> 3) * 64;
  const f32x4 Z4 = {0.f, 0.f, 0.f, 0.f};

  #pragma unroll 4
  for (int i = 0; i < 32; ++i) {
    int e = i * 256 + tid;
    int nl = e & 63, c = e >> 6;
    float f = x[((size_t)(b * CD + c)) * NN + n0 + nl];
    __bf16 h = (__bf16)f;
    __bf16 lo = (__bf16)(f - (float)h);
    unsigned off = swz256((unsigned)nl, (unsigned)(c * 2));
    *(__bf16*)(sm + off) = h;
    *(__bf16*)(sm + 16384 + off) = lo;
  }
  __syncthreads();

  bf16x8 ah[4], al[4];
  #pragma unroll
  for (int kk = 0; kk < 4; ++kk) {
    unsigned off = swz256((unsigned)(wv * 16 + l15), (unsigned)(kk * 64 + g * 16));
    ah[kk] = *(const bf16x8*)(sm + off);
    al[kk] = *(const bf16x8*)(sm + 16384 + off);
  }

  for (int mat = 0; mat < 2; ++mat) {
    const float* gw = mat ? kw : qw;
    const float* gb = mat ? kb : qb;
    __bf16* Oh = mat ? Kh : Qh;
    __bf16* Ol = mat ? Kl : Ql;
    const float sc = mat ? 1.0f : QSCALE;
    for (int qd = 0; qd < 4; ++qd) {
      #pragma unroll 4
      for (int i = 0; i < 16; ++i) {
        int e = i * 256 + tid;
        int dl = e & 31, c = e >> 5;
        float f = gw[c * CD + qd * 32 + dl];
        __bf16 h = (__bf16)f;
        __bf16 lo = (__bf16)(f - (float)h);
        unsigned off = swz256((unsigned)dl, (unsigned)(c * 2));
        *(__bf16*)(sm + 32768 + off) = h;
        *(__bf16*)(sm + 40960 + off) = lo;
      }
      __syncthreads();
      #pragma unroll
      for (int fr = 0; fr < 2; ++fr) {
        f32x4 acc = Z4;
        #pragma unroll
        for (int kk = 0; kk < 4; ++kk) {
          unsigned off = swz256((unsigned)(fr * 16 + l15), (unsigned)(kk * 64 + g * 16));
          bf16x8 bh = *(const bf16x8*)(sm + 32768 + off);
          bf16x8 bl = *(const bf16x8*)(sm + 40960 + off);
          acc = __builtin_amdgcn_mfma_f32_16x16x32_bf16(ah[kk], bh, acc, 0, 0, 0);
          acc = __builtin_amdgcn_mfma_f32_16x16x32_bf16(ah[kk], bl, acc, 0, 0, 0);
          acc = __builtin_amdgcn_mfma_f32_16x16x32_bf16(al[kk], bh, acc, 0, 0, 0);
        }
        const int dout = qd * 32 + fr * 16 + l15;
        const float bias = gb[dout];
        #pragma unroll
        for (int r = 0; r < 4; ++r) {
          int row = n0 + wv * 16 + g * 4 + r;
          float v = (acc[r] + bias) * sc;
          __bf16 h = (__bf16)v;
          __bf16 lo = (__bf16)(v - (float)h);
          size_t go = ((size_t)(b * NN + row)) * CD + dout;
          Oh[go] = h;
          Ol[go] = lo;
        }
      }
      __syncthreads();
    }
  }

  f32x4 accV[8];
  #pragma unroll
  for (int i = 0; i < 8; ++i) accV[i] = Z4;
  for (int qd = 0; qd < 4; ++qd) {
    #pragma unroll 4
    for (int i = 0; i < 16; ++i) {
      int e = i * 256 + tid;
      int dl = e & 31, c = e >> 5;
      float f = vw[c * CD + qd * 32 + dl];
      *(__bf16*)(sm + 32768 + swz256((unsigned)dl, (unsigned)(c * 2))) = (__bf16)f;
    }
    __syncthreads();
    #pragma unroll
    for (int fr = 0; fr < 2; ++fr) {
      f32x4 acc = accV[qd * 2 + fr];
      #pragma unroll
      for (int kk = 0; kk < 4; ++kk) {
        unsigned off = swz256((unsigned)(fr * 16 + l15), (unsigned)(kk * 64 + g * 16));
        bf16x8 bh = *(const bf16x8*)(sm + 32768 + off);
        acc = __builtin_amdgcn_mfma_f32_16x16x32_bf16(ah[kk], bh, acc, 0, 0, 0);
      }
      accV[qd * 2 + fr] = acc;
    }
    __syncthreads();
  }
  #pragma unroll
  for (int df = 0; df < 8; ++df) {
    int dout = df * 16 + l15;
    float bias = vb[dout];
    #pragma unroll
    for (int r = 0; r < 4; ++r) {
      int row = wv * 16 + g * 4 + r;
      *(__bf16*)(sm + 32768 + (row * 132 + dout) * 2) = (__bf16)(accV[df][r] + bias);
    }
  }
  __syncthreads();
  #pragma unroll 4
  for (int i = 0; i < 32; ++i) {
    int e = i * 256 + tid;
    int nl = e & 63, dout = e >> 6;
    __bf16 v = *(const __bf16*)(sm + 32768 + (nl * 132 + dout) * 2);
    Vt[((size_t)(b * CD + dout)) * NN + n0 + nl] = v;
  }
}

// ---------------------------------------------------------------------------
// Kernel 2: flash attention v6.
//  v5 (swapped QK^T, in-register P transpose) + cross-tile pipeline:
//  PV(t-1) issued alongside softmax(t) (independent -> MFMA || VALU overlap).
//  V triple-buffered (PV reads tile t-1 while commit writes t+1); K single.
//  Rescale order: accO += PV(t-1), then *= alpha(t).
// ---------------------------------------------------------------------------
__global__ __launch_bounds__(256, 2) void attn_kernel(
    const __bf16* __restrict__ Qh, const __bf16* __restrict__ Ql,
    const __bf16* __restrict__ Kh, const __bf16* __restrict__ Kl,
    const __bf16* __restrict__ Vt, const float* __restrict__ x,
    const float* __restrict__ pw, const float* __restrict__ pb,
    float* __restrict__ out)
{
  // loop: KH:[0,16384) KL:[16384,32768) V3:[32768 + vb*16384, ... 81920)
  // epilogue: O:[0,16384)  PWT:[16384,49152)
  __shared__ __align__(16) unsigned char sm[81920];
  const int tid = threadIdx.x;
  const int lane = tid & 63, wv = tid >> 6;
  const int l15 = lane & 15, g = lane >> 4;
  const int b = blockIdx.x & 7;           // batch -> XCD (round-robin dispatch)
  const int q0 = (blockIdx.x >> 3) * 64;
  const f32x4 Z4 = {0.f, 0.f, 0.f, 0.f};

  bf16x8 qh[4], ql[4];
  #pragma unroll
  for (int kk = 0; kk < 4; ++kk) {
    size_t off = ((size_t)(b * NN + q0 + wv * 16 + l15)) * CD + kk * 32 + g * 8;
    qh[kk] = *(const bf16x8*)(Qh + off);
    ql[kk] = *(const bf16x8*)(Ql + off);
  }

  bf16x8 bones;
  {
    __bf16 v = (l15 == 0) ? (__bf16)1.0f : (__bf16)0.0f;
    #pragma unroll
    for (int j = 0; j < 8; ++j) bones[j] = v;
  }

  f32x4 accO[8];
  #pragma unroll
  for (int i = 0; i < 8; ++i) accO[i] = Z4;
  f32x4 accL = Z4;                 // row-sums land in l15==0 lanes (col 0)
  float mrow = -__builtin_inff();  // running max for q = l15 (one per lane)

  // deferred-PV state: pa of tile t-1 (zero => iteration 0 adds nothing)
  const int4 zi4 = {0, 0, 0, 0};
  bf16x8 paA = __builtin_bit_cast(bf16x8, zi4);
  bf16x8 paB = __builtin_bit_cast(bf16x8, zi4);

  // staging (reg-staged) with hoisted per-lane offsets
  bf16x8 pkh[4], pkl[4], pvv[4];
  const int rK = tid >> 4, sK = tid & 15;
  const int rV = tid >> 3, sV = tid & 7;
  const __bf16* bKh = Kh + (size_t)(b * NN) * CD;
  const __bf16* bKl = Kl + (size_t)(b * NN) * CD;
  const __bf16* bVt = Vt + (size_t)(b * CD) * NN;
  int offK[4], offV[4];
  #pragma unroll
  for (int i = 0; i < 4; ++i) {
    offK[i] = (i * 16 + rK) * CD + sK * 8;
    offV[i] = (i * 32 + rV) * NN + sV * 8;
  }
  const int baseAddr = ((g & 1) * 32 + l15) * 4;
  const int addrA = (g * 4) * 4;

  #define ISSUE(KTOFFK, KTOFFV)                                                \
    {                                                                          \
      _Pragma("unroll")                                                        \
      for (int i = 0; i < 4; ++i) {                                            \
        pkh[i] = *(const bf16x8*)(bKh + (KTOFFK) + offK[i]);                   \
        pkl[i] = *(const bf16x8*)(bKl + (KTOFFK) + offK[i]);                   \
        pvv[i] = *(const bf16x8*)(bVt + (KTOFFV) + offV[i]);                   \
      }                                                                        \
    }
  #define COMMIT_K()                                                           \
    {                                                                          \
      _Pragma("unroll")                                                        \
      for (int i = 0; i < 4; ++i) {                                            \
        unsigned o_ = swz256((unsigned)(i * 16 + rK), (unsigned)(sK * 16));    \
        *(bf16x8*)(sm + o_) = pkh[i];                                          \
        *(bf16x8*)(sm + 16384 + o_) = pkl[i];                                  \
      }                                                                        \
    }
  #define COMMIT_V(VB)                                                         \
    {                                                                          \
      _Pragma("unroll")                                                        \
      for (int i = 0; i < 4; ++i) {                                            \
        *(bf16x8*)(sm + 32768 + (VB) * 16384 +                                 \
                   swz128((unsigned)(i * 32 + rV), (unsigned)(sV * 16))) = pvv[i]; \
      }                                                                        \
    }

  ISSUE(0, 0);
  COMMIT_K();
  COMMIT_V(0);
  COMMIT_V(2);   // dummy fill so iteration 0's PV(-1) reads finite values
  __syncthreads();

  int ktoffK = KV * CD, ktoffV = KV;     // uniform, bumped per tile
  int vb_w = 1, vb_r = 2;                // V write (t+1)%3, read (t-1)%3
  for (int kt = 0; kt < 64; ++kt) {
    if (kt < 63) ISSUE(ktoffK, ktoffV);
    ktoffK += KV * CD;
    ktoffV += KV;
    __builtin_amdgcn_sched_barrier(0);   // pin load issue before MFMAs

    // S^T = K * Q^T (swapped): s4[kf][r] = P[key=kf*16+g*4+r][q=l15]
    f32x4 s4[4];
    #pragma unroll
    for (int kf = 0; kf < 4; ++kf) s4[kf] = Z4;
    __builtin_amdgcn_s_setprio(1);
    #pragma unroll
    for (int kf = 0; kf < 4; ++kf) {
      #pragma unroll
      for (int kk = 0; kk < 4; ++kk) {
        unsigned off = swz256((unsigned)(kf * 16 + l15), (unsigned)(kk * 64 + g * 16));
        bf16x8 bh = *(const bf16x8*)(sm + off);
        bf16x8 bl = *(const bf16x8*)(sm + 16384 + off);
        s4[kf] = __builtin_amdgcn_mfma_f32_16x16x32_bf16(bh, qh[kk], s4[kf], 0, 0, 0);
        s4[kf] = __builtin_amdgcn_mfma_f32_16x16x32_bf16(bl, qh[kk], s4[kf], 0, 0, 0);
        s4[kf] = __builtin_amdgcn_mfma_f32_16x16x32_bf16(bh, ql[kk], s4[kf], 0, 0, 0);
      }
    }
    __builtin_amdgcn_s_setprio(0);

    // PV(t-1): independent of s4 -> MFMA pipe fills while VALU does softmax.
    {
      const unsigned vbase = 32768u + (unsigned)vb_r * 16384u;
      accL = __builtin_amdgcn_mfma_f32_16x16x32_bf16(paA, bones, accL, 0, 0, 0);
      accL = __builtin_amdgcn_mfma_f32_16x16x32_bf16(paB, bones, accL, 0, 0, 0);
      #pragma unroll
      for (int df = 0; df < 8; ++df) {
        bf16x8 bv0 = *(const bf16x8*)(sm + vbase +
                       swz128((unsigned)(df * 16 + l15), (unsigned)(g * 16)));
        bf16x8 bv1 = *(const bf16x8*)(sm + vbase +
                       swz128((unsigned)(df * 16 + l15), (unsigned)(64 + g * 16)));
        accO[df] = __builtin_amdgcn_mfma_f32_16x16x32_bf16(paA, bv0, accO[df], 0, 0, 0);
        accO[df] = __builtin_amdgcn_mfma_f32_16x16x32_bf16(paB, bv1, accO[df], 0, 0, 0);
      }
    }

    // online softmax for q=l15 (overlaps the PV MFMAs above)
    float mx = fmaxf(fmaxf(s4[0][0], s4[0][1]), fmaxf(s4[0][2], s4[0][3]));
    #pragma unroll
    for (int kf = 1; kf < 4; ++kf) {
      mx = fmaxf(mx, fmaxf(fmaxf(s4[kf][0], s4[kf][1]),
                           fmaxf(s4[kf][2], s4[kf][3])));
    }
    mx = fmaxf(mx, __shfl_xor(mx, 16));
    mx = fmaxf(mx, __shfl_xor(mx, 32));
    const float mn = fmaxf(mrow, mx);
    #pragma unroll
    for (int kf = 0; kf < 4; ++kf) {
      #pragma unroll
      for (int r = 0; r < 4; ++r) s4[kf][r] = exp2f(s4[kf][r] - mn);
    }

    // P(t) -> bf16 PV A-fragments in registers (used NEXT iteration)
    int c01[4], c23[4];
    #pragma unroll
    for (int kf = 0; kf < 4; ++kf) {
      c01[kf] = cvt_pk_bf16(s4[kf][0], s4[kf][1]);
      c23[kf] = cvt_pk_bf16(s4[kf][2], s4[kf][3]);
    }
    bf16x8 npa[2];
    #pragma unroll
    for (int kk2 = 0; kk2 < 2; ++kk2) {
      int w[4];
      #pragma unroll
      for (int wi = 0; wi < 4; ++wi) {
        int se = (wi & 1) ? c23[kk2 * 2] : c01[kk2 * 2];
        int so = (wi & 1) ? c23[kk2 * 2 + 1] : c01[kk2 * 2 + 1];
        int a = baseAddr + (wi >> 1) * 64;
        int ve = __builtin_amdgcn_ds_bpermute(a, se);
        int vo = __builtin_amdgcn_ds_bpermute(a, so);
        w[wi] = (g < 2) ? ve : vo;
      }
      int4 wv4 = {w[0], w[1], w[2], w[3]};
      npa[kk2] = __builtin_bit_cast(bf16x8, wv4);
    }

    // rescale accO/accL (AFTER PV(t-1) add): m(t-1)-scale -> m(t)-scale.
    {
      float alpha = exp2f(mrow - mn);
      int aw = __builtin_bit_cast(int, alpha);
      #pragma unroll
      for (int r = 0; r < 4; ++r) {
        float ar = __builtin_bit_cast(float,
                     __builtin_amdgcn_ds_bpermute(addrA + r * 4, aw));
        accL[r] *= ar;
        #pragma unroll
        for (int df = 0; df < 8; ++df) accO[df][r] *= ar;
      }
    }
    mrow = mn;
    paA = npa[0];
    paB = npa[1];

    __syncthreads();                  // all waves done reading K of tile kt
    if (kt < 63) { COMMIT_K(); COMMIT_V(vb_w); }
    __syncthreads();
    vb_w = (vb_w == 2) ? 0 : vb_w + 1;
    vb_r = (vb_r == 2) ? 0 : vb_r + 1;
  }
  #undef ISSUE
  #undef COMMIT_K
  #undef COMMIT_V

  // drain: PV(63)  (vb_r == 63%3 == 0 here)
  {
    const unsigned vbase = 32768u + (unsigned)vb_r * 16384u;
    accL = __builtin_amdgcn_mfma_f32_16x16x32_bf16(paA, bones, accL, 0, 0, 0);
    accL = __builtin_amdgcn_mfma_f32_16x16x32_bf16(paB, bones, accL, 0, 0, 0);
    #pragma unroll
    for (int df = 0; df < 8; ++df) {
      bf16x8 bv0 = *(const bf16x8*)(sm + vbase +
                     swz128((unsigned)(df * 16 + l15), (unsigned)(g * 16)));
      bf16x8 bv1 = *(const bf16x8*)(sm + vbase +
                     swz128((unsigned)(df * 16 + l15), (unsigned)(64 + g * 16)));
      accO[df] = __builtin_amdgcn_mfma_f32_16x16x32_bf16(paA, bv0, accO[df], 0, 0, 0);
      accO[df] = __builtin_amdgcn_mfma_f32_16x16x32_bf16(paB, bv1, accO[df], 0, 0, 0);
    }
  }
  __syncthreads();   // before epilogue aliases the K/V regions

  // epilogue: broadcast row-sums, O/l -> bf16 LDS, proj + bias + residual
  float rl[4];
  #pragma unroll
  for (int r = 0; r < 4; ++r) {
    float lv = __shfl(accL[r], lane & 48);
    rl[r] = 1.0f / lv;
  }
  #pragma unroll
  for (int df = 0; df < 8; ++df) {
    #pragma unroll
    for (int r = 0; r < 4; ++r) {
      unsigned row = (unsigned)(wv * 16 + g * 4 + r);
      *(__bf16*)(sm + swz256(row, (unsigned)((df * 16 + l15) * 2))) =
          (__bf16)(accO[df][r] * rl[r]);
    }
  }
  #pragma unroll 4
  for (int i = 0; i < 16; ++i) {  // pwT[dout][c] bf16 at 16384
    int e = i * 256 + tid;
    int c = e >> 5, d4 = e & 31;
    const float4 w4 = *(const float4*)(pw + c * CD + d4 * 4);
    *(__bf16*)(sm + 16384 + swz256((unsigned)(d4 * 4 + 0), (unsigned)(c * 2))) = (__bf16)w4.x;
    *(__bf16*)(sm + 16384 + swz256((unsigned)(d4 * 4 + 1), (unsigned)(c * 2))) = (__bf16)w4.y;
    *(__bf16*)(sm + 16384 + swz256((unsigned)(d4 * 4 + 2), (unsigned)(c * 2))) = (__bf16)w4.z;
    *(__bf16*)(sm + 16384 + swz256((unsigned)(d4 * 4 + 3), (unsigned)(c * 2))) = (__bf16)w4.w;
  }
  __syncthreads();

  bf16x8 oa[4];
  #pragma unroll
  for (int kk = 0; kk < 4; ++kk)
    oa[kk] = *(const bf16x8*)(sm + swz256((unsigned)(wv * 16 + l15),
                                          (unsigned)(kk * 64 + g * 16)));
  #pragma unroll
  for (int df = 0; df < 8; ++df) {
    f32x4 acc = Z4;
    #pragma unroll
    for (int kk = 0; kk < 4; ++kk) {
      bf16x8 bw = *(const bf16x8*)(sm + 16384 +
                    swz256((unsigned)(df * 16 + l15), (unsigned)(kk * 64 + g * 16)));
      acc = __builtin_amdgcn_mfma_f32_16x16x32_bf16(oa[kk], bw, acc, 0, 0, 0);
    }
    const int cc = df * 16 + l15;
    const float bias = pb[cc];
    #pragma unroll
    for (int r = 0; r < 4; ++r) {
      int row = q0 + wv * 16 + g * 4 + r;
      float val = acc[r] + bias + x[((size_t)(b * CD + cc)) * NN + row];
      out[((size_t)(b * NN + row)) * CD + cc] = val;
    }
  }
}

// ---------------------------------------------------------------------------
extern "C" void kernel_launch(void* const* d_in, const int* in_sizes, int n_in,
                              void* d_out, int out_size, void* d_ws, size_t ws_size,
                              hipStream_t stream) {
  (void)in_sizes; (void)n_in; (void)out_size; (void)ws_size;
  const float* x  = (const float*)d_in[0];
  const float* qw = (const float*)d_in[1];
  const float* qb = (const float*)d_in[2];
  const float* kw = (const float*)d_in[3];
  const float* kb = (const float*)d_in[4];
  const float* vw = (const float*)d_in[5];
  const float* vb = (const float*)d_in[6];
  const float* pw = (const float*)d_in[7];
  const float* pb = (const float*)d_in[8];
  float* out = (float*)d_out;

  const size_t SZ = (size_t)NB * NN * CD;  // 4.19M elems per buffer
  __bf16* Qh = (__bf16*)d_ws;              // ws usage: 5 * 8.39 MB = 41.9 MB
  __bf16* Ql = Qh + SZ;
  __bf16* Kh = Ql + SZ;
  __bf16* Kl = Kh + SZ;
  __bf16* Vt = Kl + SZ;

  dim3 grid(512), blk(256);                // 1-D: bid&7 = batch = XCD
  qkv_kernel<<<grid, blk, 0, stream>>>(x, qw, qb, kw, kb, vw, vb,
                                       Qh, Ql, Kh, Kl, Vt);
  attn_kernel<<<grid, blk, 0, stream>>>(Qh, Ql, Kh, Kl, Vt, x, pw, pb, out);
}